// Round 12
// baseline (166.348 us; speedup 1.0000x reference)
//
#include <hip/hip_runtime.h>

#define B_SZ 1024
#define DIN 512
#define HH 512   // H
#define DOUT 512

typedef short bf16x8 __attribute__((ext_vector_type(8)));
typedef float f32x4 __attribute__((ext_vector_type(4)));

__device__ __forceinline__ unsigned short f2bf(float f) {
    unsigned int u = __float_as_uint(f);
    u += 0x7FFFu + ((u >> 16) & 1u);          // RTNE
    return (unsigned short)(u >> 16);
}
__device__ __forceinline__ float bf2f(unsigned short s) {
    return __uint_as_float(((unsigned int)s) << 16);
}

// pack 8 fp32 -> 8 bf16 (term==1 -> lo residual, else hi)
__device__ __forceinline__ uint4 cvt8(const float4& a0, const float4& a1, int term) {
    const float av[8] = {a0.x, a0.y, a0.z, a0.w, a1.x, a1.y, a1.z, a1.w};
    unsigned int p[4];
    #pragma unroll
    for (int q = 0; q < 4; ++q) {
        float f0 = av[2 * q], f1 = av[2 * q + 1];
        unsigned short h0 = f2bf(f0), h1 = f2bf(f1);
        if (term == 1) { h0 = f2bf(f0 - bf2f(h0)); h1 = f2bf(f1 - bf2f(h1)); }
        p[q] = (unsigned int)h0 | ((unsigned int)h1 << 16);
    }
    uint4 v; v.x = p[0]; v.y = p[1]; v.z = p[2]; v.w = p[3];
    return v;
}

// async global->LDS, 16B/lane. LDS dest = WAVE-UNIFORM base + lane*16 (m104);
// global src is per-lane (m173). Proven correct in r7-r11 runs.
__device__ __forceinline__ void gload_lds16(const void* g, void* l) {
    __builtin_amdgcn_global_load_lds(
        (__attribute__((address_space(1))) void*)g,
        (__attribute__((address_space(3))) void*)l, 16, 0, 0);
}

// counted vmem wait (T4): wait until <= N vmem ops outstanding (FIFO).
template <int N>
__device__ __forceinline__ void waitcnt_vm() {
    asm volatile("s_waitcnt vmcnt(%0)" :: "n"(N) : "memory");
}
__device__ __forceinline__ void SB() { __builtin_amdgcn_sched_barrier(0); }

// ---------------------------------------------------------------------------
// bf16 hi/lo split GEMM scheme (K'=1536 = 3 terms x 512):
//   C = AhiWhi + AloWhi + AhiWlo  (~fp32 accurate)
// ---------------------------------------------------------------------------
__device__ __forceinline__ void convW_body(const float* __restrict__ W,
                                           uint4* __restrict__ dst, int t) {
    const int lane = t & 63;
    const int fb   = t >> 6;         // ks*32 + nf
    const int ks   = fb >> 5;
    const int nf   = fb & 31;
    const int col  = nf * 16 + (lane & 15);
    const int kb   = ks * 32 + ((lane >> 4) << 3);
    const int term = kb >> 9;        // 0,1,2 -> hi,hi,lo
    const int c0   = kb & 511;
    unsigned short o[8];
    #pragma unroll
    for (int j = 0; j < 8; ++j) {
        const float f = W[(size_t)(c0 + j) * 512 + col];
        unsigned short hi = f2bf(f);
        o[j] = (term == 2) ? f2bf(f - bf2f(hi)) : hi;
    }
    uint4 v;
    v.x = (unsigned int)o[0] | ((unsigned int)o[1] << 16);
    v.y = (unsigned int)o[2] | ((unsigned int)o[3] << 16);
    v.z = (unsigned int)o[4] | ((unsigned int)o[5] << 16);
    v.w = (unsigned int)o[6] | ((unsigned int)o[7] << 16);
    dst[t] = v;
}

// ---------------------------------------------------------------------------
// scan weight packs:
//  wdg[i*64+l] = diag elem (row i, col 64*(i>>6)+l), masked (col>i), row-511 pad
//  wbk v2, PER-PARITY consumption order (for wave-private staging):
//    chunk C, par p, tile t (s = 2t+p), slot k, lane l at f2 index
//    CB(C) + p*2048*NK + t*64*NK + k*64 + l   — contiguous per (C,p).
// ---------------------------------------------------------------------------
template <int C>
__device__ __forceinline__ void pack_bulk(const float* __restrict__ W_hh,
                                          const float* __restrict__ b_hh,
                                          float2* __restrict__ wbk, int e) {
    constexpr int NK = 7 - C;
    constexpr int CB = (C==0?0:C==1?7:C==2?13:C==3?18:C==4?22:C==5?25:27) * 4096;
    const int par = e / (2048 * NK);         // compile-time divisor -> magic mul
    const int r1  = e - par * (2048 * NK);
    const int t   = r1 / (64 * NK);
    const int r2  = r1 - t * (64 * NK);
    const int k   = r2 >> 6;                 // r2 / 64
    const int l   = r2 & 63;
    const int row = 64 * C + 2 * t + par;
    const int col = 64 * (C + 1 + k) + l;
    float2 o;
    o.x = W_hh[(size_t)row * 512 + col];
    o.y = b_hh[(size_t)row * 512 + col];
    wbk[CB + e] = o;
}

// ---------------------------------------------------------------------------
// prep_all (block-range dispatch), 1344 blocks — same ranges as r5-r11.
// ---------------------------------------------------------------------------
__global__ __launch_bounds__(256)
void prep_all(const float* __restrict__ W_hh, const float* __restrict__ b_hh,
              float2* __restrict__ wdg, float2* __restrict__ wbk,
              const float* __restrict__ W_in, uint4* __restrict__ Bin,
              const float* __restrict__ W_out, uint4* __restrict__ Bout) {
    const int b = blockIdx.x;
    const int tid = threadIdx.x;
    if (b < 128) {
        const int idx = b * 256 + tid;       // over 512*64
        const int i = idx >> 6, l = idx & 63;
        float2 o;
        if (i < 511 && l > (i & 63)) {
            const int col = ((i >> 6) << 6) + l;
            o.x = W_hh[(size_t)i * 512 + col];
            o.y = b_hh[(size_t)i * 512 + col];
        } else { o.x = 0.0f; o.y = -1.0f; }
        wdg[idx] = o;
    } else if (b < 576) {
        const int rb = b - 128;
        if      (rb < 112) pack_bulk<0>(W_hh, b_hh, wbk, (rb      ) * 256 + tid);
        else if (rb < 208) pack_bulk<1>(W_hh, b_hh, wbk, (rb - 112) * 256 + tid);
        else if (rb < 288) pack_bulk<2>(W_hh, b_hh, wbk, (rb - 208) * 256 + tid);
        else if (rb < 352) pack_bulk<3>(W_hh, b_hh, wbk, (rb - 288) * 256 + tid);
        else if (rb < 400) pack_bulk<4>(W_hh, b_hh, wbk, (rb - 352) * 256 + tid);
        else if (rb < 432) pack_bulk<5>(W_hh, b_hh, wbk, (rb - 400) * 256 + tid);
        else               pack_bulk<6>(W_hh, b_hh, wbk, (rb - 432) * 256 + tid);
    } else if (b < 960) {
        convW_body(W_in, Bin, (b - 576) * 256 + tid);
    } else {
        convW_body(W_out, Bout, (b - 960) * 256 + tid);
    }
}

// ---------------------------------------------------------------------------
// MFMA GEMM: 512 threads (8 waves = 2/SIMD). Unchanged (passing r5-r11).
// ---------------------------------------------------------------------------
template <bool ACT>
__global__ __launch_bounds__(512, 2)
void mfma_gemm(const float* __restrict__ A,    // [1024][512] fp32
               const uint4* __restrict__ Bg,   // [48][32][64] uint4
               const float* __restrict__ bias,
               float* __restrict__ C) {
    __shared__ uint4 lds[2][768];
    const int tid  = threadIdx.x;
    const int lane = tid & 63;
    const int w    = tid >> 6;
    const int mfw  = w & 3;
    const int nfw  = w >> 2;
    const int mf0  = blockIdx.x * 4;
    const int nf0  = blockIdx.y * 2;

    const int ks_s = tid >> 8;
    const int mf_s = (tid >> 6) & 3;
    const int arow = (mf0 + mf_s) * 16 + (lane & 15);
    const int koff = (lane >> 4) << 3;
    const int bks  = tid >> 7;
    const int bnf  = (tid >> 6) & 1;

    float4 Ra0, Ra1; uint4 R2;
    auto stage = [&](int s) {
        const int kp = (s * 2 + ks_s) * 32 + koff;
        const int c  = kp & 511;
        Ra0 = *(const float4*)&A[(size_t)arow * 512 + c];
        Ra1 = *(const float4*)&A[(size_t)arow * 512 + c + 4];
        if (tid < 256)
            R2 = Bg[(size_t)((s * 2 + bks) * 32 + nf0 + bnf) * 64 + lane];
    };
    auto write_tile = [&](int buf, int s) {
        const int kp = (s * 2 + ks_s) * 32 + koff;
        lds[buf][ks_s * 256 + mf_s * 64 + lane] = cvt8(Ra0, Ra1, kp >> 9);
        if (tid < 256)
            lds[buf][512 + bks * 128 + bnf * 64 + lane] = R2;
    };

    f32x4 acc = {0.f, 0.f, 0.f, 0.f};

    stage(0);
    write_tile(0, 0);
    stage(1);
    __syncthreads();

    for (int s = 0; s < 24; ++s) {
        const int cur = s & 1;
        if (s + 1 < 24) write_tile(cur ^ 1, s + 1);
        if (s + 2 < 24) stage(s + 2);
        __builtin_amdgcn_sched_barrier(0);

        bf16x8 aF0 = *(const bf16x8*)&lds[cur][          mfw * 64 + lane];
        bf16x8 aF1 = *(const bf16x8*)&lds[cur][256     + mfw * 64 + lane];
        bf16x8 bF0 = *(const bf16x8*)&lds[cur][512     + nfw * 64 + lane];
        bf16x8 bF1 = *(const bf16x8*)&lds[cur][512+128 + nfw * 64 + lane];
        acc = __builtin_amdgcn_mfma_f32_16x16x32_bf16(aF0, bF0, acc, 0, 0, 0);
        acc = __builtin_amdgcn_mfma_f32_16x16x32_bf16(aF1, bF1, acc, 0, 0, 0);
        __syncthreads();
    }

    const int colg  = (nf0 + nfw) * 16 + (lane & 15);
    const float bv  = bias[colg];
    const int rbase = (mf0 + mfw) * 16 + ((lane >> 4) << 2);
    #pragma unroll
    for (int r = 0; r < 4; ++r) {
        float v = acc[r] + bv;
        if (ACT) { v = fmaxf(v, 0.f); v = v * v; }
        C[(size_t)(rbase + r) * 512 + colg] = v;
    }
}

// ---------------------------------------------------------------------------
// Sequential triangular scan, v12: WAVE-PRIVATE LDS pipelines, no per-tile
// barriers. 512 blocks x 4 waves (2 rows x 2 s-parity halves, v11 layout).
//
// v11 evidence: 48us of its 54 was per-tile structure (shared staging +
// inter-wave barrier skew), untouched by TLP (v11) or counted vmcnt at
// shared buffers (v9). v12 removes the coupling entirely: the bulk pack is
// per-(chunk,parity) contiguous, so each wave stages ITS OWN stream into
// ITS OWN 16KB LDS region (4 x 4KB buffers) via gload_lds and gates only
// on its own counted vmcnt (wait 2U steady-state, U=ceil(NK/2) loads/tile;
// FIFO -> tile t resident, t+1..t+2 in flight; compute-before-stage makes
// buffer reuse safe by program order within the wave). Inter-wave syncs:
// 2 per chunk (hr[C] handoff, lgkmcnt+s_barrier only -> prefetches stay in
// flight; partner's prefetch overlaps owner's diag). Diag + per-column FP
// order identical to v11 (passing).
// ---------------------------------------------------------------------------
template <int C>
__device__ __forceinline__ void scan_chunk(const float2* __restrict__ wdg,
                                           const char* __restrict__ wbk,
                                           char* __restrict__ myLds,
                                           float (* __restrict__ comm)[64],
                                           float hrp[8], int lane, int row_l,
                                           int par) {
    constexpr int NK = 7 - C;
    constexpr int CB = (C==0?0:C==1?7:C==2?13:C==3?18:C==4?22:C==5?25:C==6?27:27) * 32768;
    constexpr int U  = (NK + 1) / 2;         // gload16 per tile (<=512B overrun ok)
    constexpr int TB = NK * 512;             // tile bytes in pack
    const char* gch = wbk + CB + par * (32 * TB);

    auto stage = [&](int t) {
        const char* g = gch + t * TB;
        char* l = myLds + ((t & 3) << 12);   // private 4KB buffer
        #pragma unroll
        for (int u = 0; u < U; ++u)
            gload_lds16(g + (u << 10) + lane * 16, l + (u << 10));
    };
    if constexpr (NK > 0) { stage(0); stage(1); stage(2); }   // 3-deep prefetch
    SB();

    // partial handoff: odd wave's bulk partial for group C -> even wave.
    // lgkmcnt-only barrier: LDS write visible, vmcnt prefetches stay in flight.
    if (par == 1) comm[row_l][lane] = hrp[C];
    asm volatile("s_waitcnt lgkmcnt(0)" ::: "memory");
    __builtin_amdgcn_s_barrier();
    SB();

    if (par == 0) {                          // serial diag (v8/v11 window)
        hrp[C] += comm[row_l][lane];
        const float2* dptr = wdg + (64 * C) * 64 + lane;
        float2 Wd[16];
        #pragma unroll
        for (int q = 0; q < 16; ++q) Wd[q] = dptr[q * 64];
        for (int t = 0; t < 4; ++t) {
            #pragma unroll
            for (int q = 0; q < 16; ++q) {
                const int s = t * 16 + q;
                if (!(C == 7 && s == 63)) {  // no global step 511
                    const float hi = __uint_as_float(
                        __builtin_amdgcn_readlane(__float_as_uint(hrp[C]), s));
                    const float tv = fmaf(hi, Wd[q].x, Wd[q].y);
                    const float rv = fmaxf(tv, 0.f);
                    hrp[C] = fmaf(rv, rv, hrp[C]);
                }
                if (t < 3) Wd[q] = dptr[(s + 16) * 64];
            }
        }
        comm[row_l][lane] = hrp[C];          // broadcast final
    }
    asm volatile("s_waitcnt lgkmcnt(0)" ::: "memory");
    __builtin_amdgcn_s_barrier();
    SB();

    if constexpr (NK > 0) {
        const float hsrc = (par == 0) ? hrp[C] : comm[row_l][lane];
        const float2* lf = (const float2*)myLds;

        auto compute = [&](int t) {          // wave's s = 2t+par of tile t
            const float hi = __uint_as_float(__builtin_amdgcn_readlane(
                __float_as_uint(hsrc), 2 * t + par));
            #pragma unroll
            for (int k = 0; k < NK; ++k) {
                const float2 wv = lf[((t & 3) << 9) + (k << 6) + lane];
                const float tv = fmaf(hi, wv.x, wv.y);
                const float rv = fmaxf(tv, 0.f);
                hrp[C + 1 + k] = fmaf(rv, rv, hrp[C + 1 + k]);
            }
        };
        // steady state: entry outstanding <= {t,t+1,t+2}; wait 2U -> tile t
        // resident. compute BEFORE stage(t+3): ds_reads of buf t&3 complete
        // (lgkm-forced by fma uses) before the DMA rewrite of that buffer.
        #pragma unroll 4
        for (int t = 0; t < 28; ++t) {
            waitcnt_vm<2 * U>(); SB();
            compute(t);
            stage(t + 3); SB();
        }
        waitcnt_vm<2 * U>(); SB(); compute(28); stage(31); SB();
        waitcnt_vm<2 * U>(); SB(); compute(29);
        waitcnt_vm<U>();     SB(); compute(30);
        waitcnt_vm<0>();     SB(); compute(31);
    }
}

__global__ __launch_bounds__(256, 2)
void scan_kernel(const float2* __restrict__ wdg, const float2* __restrict__ wbk,
                 float* __restrict__ h) {
    __shared__ __align__(16) char smb[4][16384];    // 16KB private per wave
    __shared__ float comm[2][64];                   // per-row handoff, 512B
    const int tid   = threadIdx.x;
    const int lane  = tid & 63;
    const int w     = tid >> 6;
    const int row_l = w & 1;                 // row slot in block
    const int par   = w >> 1;                // s-parity half (0 = diag owner)
    float* hrow = h + (size_t)(blockIdx.x * 2 + row_l) * HH;

    float hrp[8];
    #pragma unroll
    for (int k = 0; k < 8; ++k) hrp[k] = (par == 0) ? hrow[lane + 64 * k] : 0.f;

    char* myLds = &smb[w][0];
    const char* wb = (const char*)wbk;

    scan_chunk<0>(wdg, wb, myLds, comm, hrp, lane, row_l, par);
    scan_chunk<1>(wdg, wb, myLds, comm, hrp, lane, row_l, par);
    scan_chunk<2>(wdg, wb, myLds, comm, hrp, lane, row_l, par);
    scan_chunk<3>(wdg, wb, myLds, comm, hrp, lane, row_l, par);
    scan_chunk<4>(wdg, wb, myLds, comm, hrp, lane, row_l, par);
    scan_chunk<5>(wdg, wb, myLds, comm, hrp, lane, row_l, par);
    scan_chunk<6>(wdg, wb, myLds, comm, hrp, lane, row_l, par);
    scan_chunk<7>(wdg, wb, myLds, comm, hrp, lane, row_l, par);

    // group k finalized at chunk k's diag in the even-parity wave
    if (par == 0) {
        #pragma unroll
        for (int k = 0; k < 8; ++k) hrow[lane + 64 * k] = hrp[k];
    }
}

// ---------------------------------------------------------------------------
// workspace layout (6.2 MB):
//   [0x000000, 0x040000) wdg  (512*64 f2 = 256 KB)
//   [0x040000, 0x120000) wbk  (114688 f2 = 896 KB, per-parity pack)
//   [0x120000, 0x320000) h    (1024*512 fp32 = 2 MB)
//   [0x320000, 0x4A0000) Bin  (48*32*64 uint4 = 1.5 MB)
//   [0x4A0000, 0x620000) Bout (1.5 MB)
// ---------------------------------------------------------------------------
extern "C" void kernel_launch(void* const* d_in, const int* in_sizes, int n_in,
                              void* d_out, int out_size, void* d_ws, size_t ws_size,
                              hipStream_t stream) {
    const float* x     = (const float*)d_in[0];
    const float* W_in  = (const float*)d_in[1];
    const float* b_in  = (const float*)d_in[2];
    const float* W_hh  = (const float*)d_in[3];
    const float* b_hh  = (const float*)d_in[4];
    const float* W_out = (const float*)d_in[5];
    const float* b_out = (const float*)d_in[6];
    float* out = (float*)d_out;

    char* ws = (char*)d_ws;
    float2* wdg  = (float2*)ws;
    float2* wbk  = (float2*)(ws + 0x040000u);
    float*  h    = (float*)(ws + 0x120000u);
    uint4*  Bin  = (uint4*)(ws + 0x320000u);
    uint4*  Bout = (uint4*)(ws + 0x4A0000u);

    // 1) prep: scan-weight packs + W_in/W_out bf16 hi/lo frag-linear split
    prep_all<<<dim3(1344), dim3(256), 0, stream>>>(W_hh, b_hh, wdg, wbk,
                                                   W_in, Bin, W_out, Bout);

    // 2) h0 = relu^2(x @ W_in + b_in)  (A-side split fused into staging)
    mfma_gemm<true><<<dim3(16, 16), dim3(512), 0, stream>>>(x, Bin, b_in, h);

    // 3) sequential triangular scan, in-place on h (wave-private pipelines)
    scan_kernel<<<dim3(512), dim3(256), 0, stream>>>(wdg, wbk, h);

    // 4) out = h @ W_out + b_out  (A-side split fused into staging)
    mfma_gemm<false><<<dim3(16, 16), dim3(512), 0, stream>>>(h, Bout, b_out, out);
}

// Round 13
// 149.429 us; speedup vs baseline: 1.1132x; 1.1132x over previous
//
#include <hip/hip_runtime.h>

#define B_SZ 1024
#define DIN 512
#define HH 512   // H
#define DOUT 512

typedef short bf16x8 __attribute__((ext_vector_type(8)));
typedef float f32x4 __attribute__((ext_vector_type(4)));

__device__ __forceinline__ unsigned short f2bf(float f) {
    unsigned int u = __float_as_uint(f);
    u += 0x7FFFu + ((u >> 16) & 1u);          // RTNE
    return (unsigned short)(u >> 16);
}
__device__ __forceinline__ float bf2f(unsigned short s) {
    return __uint_as_float(((unsigned int)s) << 16);
}

// pack 8 fp32 -> 8 bf16 (term==1 -> lo residual, else hi)
__device__ __forceinline__ uint4 cvt8(const float4& a0, const float4& a1, int term) {
    const float av[8] = {a0.x, a0.y, a0.z, a0.w, a1.x, a1.y, a1.z, a1.w};
    unsigned int p[4];
    #pragma unroll
    for (int q = 0; q < 4; ++q) {
        float f0 = av[2 * q], f1 = av[2 * q + 1];
        unsigned short h0 = f2bf(f0), h1 = f2bf(f1);
        if (term == 1) { h0 = f2bf(f0 - bf2f(h0)); h1 = f2bf(f1 - bf2f(h1)); }
        p[q] = (unsigned int)h0 | ((unsigned int)h1 << 16);
    }
    uint4 v; v.x = p[0]; v.y = p[1]; v.z = p[2]; v.w = p[3];
    return v;
}

// async global->LDS, 16B/lane. LDS dest = WAVE-UNIFORM base + lane*16 (m104);
// global src is per-lane (m173). Proven correct in r7-r12 runs.
__device__ __forceinline__ void gload_lds16(const void* g, void* l) {
    __builtin_amdgcn_global_load_lds(
        (__attribute__((address_space(1))) void*)g,
        (__attribute__((address_space(3))) void*)l, 16, 0, 0);
}
__device__ __forceinline__ void SB() { __builtin_amdgcn_sched_barrier(0); }

// ---------------------------------------------------------------------------
// bf16 hi/lo split GEMM scheme (K'=1536 = 3 terms x 512):
//   C = AhiWhi + AloWhi + AhiWlo  (~fp32 accurate)
// ---------------------------------------------------------------------------
__device__ __forceinline__ void convW_body(const float* __restrict__ W,
                                           uint4* __restrict__ dst, int t) {
    const int lane = t & 63;
    const int fb   = t >> 6;         // ks*32 + nf
    const int ks   = fb >> 5;
    const int nf   = fb & 31;
    const int col  = nf * 16 + (lane & 15);
    const int kb   = ks * 32 + ((lane >> 4) << 3);
    const int term = kb >> 9;        // 0,1,2 -> hi,hi,lo
    const int c0   = kb & 511;
    unsigned short o[8];
    #pragma unroll
    for (int j = 0; j < 8; ++j) {
        const float f = W[(size_t)(c0 + j) * 512 + col];
        unsigned short hi = f2bf(f);
        o[j] = (term == 2) ? f2bf(f - bf2f(hi)) : hi;
    }
    uint4 v;
    v.x = (unsigned int)o[0] | ((unsigned int)o[1] << 16);
    v.y = (unsigned int)o[2] | ((unsigned int)o[3] << 16);
    v.z = (unsigned int)o[4] | ((unsigned int)o[5] << 16);
    v.w = (unsigned int)o[6] | ((unsigned int)o[7] << 16);
    dst[t] = v;
}

// scan weight packs, consumption-ordered (r11 layout, REVERTED from v12):
//  wdg[i*64+l] = diag elem (row i, col 64*(i>>6)+l), masked (col>i), row-511 pad
//  wbk[CB + ((s*NK+k)*64+l)] = bulk elem (row 64C+s, col 64*(C+1+k)+l), no mask
template <int C>
__device__ __forceinline__ void pack_bulk(const float* __restrict__ W_hh,
                                          const float* __restrict__ b_hh,
                                          float2* __restrict__ wbk, int e) {
    constexpr int NK = 7 - C;
    constexpr int CB = (C==0?0:C==1?7:C==2?13:C==3?18:C==4?22:C==5?25:27) * 4096;
    const int s   = e / (NK * 64);           // compile-time NK -> magic mul
    const int rem = e - s * (NK * 64);
    const int row = 64 * C + s;
    const int col = 64 * (C + 1) + rem;
    float2 o;
    o.x = W_hh[(size_t)row * 512 + col];
    o.y = b_hh[(size_t)row * 512 + col];
    wbk[CB + e] = o;
}

// ---------------------------------------------------------------------------
// prep_all (block-range dispatch), 1344 blocks — r11 version verbatim.
// ---------------------------------------------------------------------------
__global__ __launch_bounds__(256)
void prep_all(const float* __restrict__ W_hh, const float* __restrict__ b_hh,
              float2* __restrict__ wdg, float2* __restrict__ wbk,
              const float* __restrict__ W_in, uint4* __restrict__ Bin,
              const float* __restrict__ W_out, uint4* __restrict__ Bout) {
    const int b = blockIdx.x;
    const int tid = threadIdx.x;
    if (b < 128) {
        const int idx = b * 256 + tid;       // over 512*64
        const int i = idx >> 6, l = idx & 63;
        float2 o;
        if (i < 511 && l > (i & 63)) {
            const int col = ((i >> 6) << 6) + l;
            o.x = W_hh[(size_t)i * 512 + col];
            o.y = b_hh[(size_t)i * 512 + col];
        } else { o.x = 0.0f; o.y = -1.0f; }
        wdg[idx] = o;
    } else if (b < 576) {
        const int rb = b - 128;
        if      (rb < 112) pack_bulk<0>(W_hh, b_hh, wbk, (rb      ) * 256 + tid);
        else if (rb < 208) pack_bulk<1>(W_hh, b_hh, wbk, (rb - 112) * 256 + tid);
        else if (rb < 288) pack_bulk<2>(W_hh, b_hh, wbk, (rb - 208) * 256 + tid);
        else if (rb < 352) pack_bulk<3>(W_hh, b_hh, wbk, (rb - 288) * 256 + tid);
        else if (rb < 400) pack_bulk<4>(W_hh, b_hh, wbk, (rb - 352) * 256 + tid);
        else if (rb < 432) pack_bulk<5>(W_hh, b_hh, wbk, (rb - 400) * 256 + tid);
        else               pack_bulk<6>(W_hh, b_hh, wbk, (rb - 432) * 256 + tid);
    } else if (b < 960) {
        convW_body(W_in, Bin, (b - 576) * 256 + tid);
    } else {
        convW_body(W_out, Bout, (b - 960) * 256 + tid);
    }
}

// ---------------------------------------------------------------------------
// MFMA GEMM: 512 threads (8 waves = 2/SIMD). Unchanged (passing r5-r12).
// ---------------------------------------------------------------------------
template <bool ACT>
__global__ __launch_bounds__(512, 2)
void mfma_gemm(const float* __restrict__ A,    // [1024][512] fp32
               const uint4* __restrict__ Bg,   // [48][32][64] uint4
               const float* __restrict__ bias,
               float* __restrict__ C) {
    __shared__ uint4 lds[2][768];
    const int tid  = threadIdx.x;
    const int lane = tid & 63;
    const int w    = tid >> 6;
    const int mfw  = w & 3;
    const int nfw  = w >> 2;
    const int mf0  = blockIdx.x * 4;
    const int nf0  = blockIdx.y * 2;

    const int ks_s = tid >> 8;
    const int mf_s = (tid >> 6) & 3;
    const int arow = (mf0 + mf_s) * 16 + (lane & 15);
    const int koff = (lane >> 4) << 3;
    const int bks  = tid >> 7;
    const int bnf  = (tid >> 6) & 1;

    float4 Ra0, Ra1; uint4 R2;
    auto stage = [&](int s) {
        const int kp = (s * 2 + ks_s) * 32 + koff;
        const int c  = kp & 511;
        Ra0 = *(const float4*)&A[(size_t)arow * 512 + c];
        Ra1 = *(const float4*)&A[(size_t)arow * 512 + c + 4];
        if (tid < 256)
            R2 = Bg[(size_t)((s * 2 + bks) * 32 + nf0 + bnf) * 64 + lane];
    };
    auto write_tile = [&](int buf, int s) {
        const int kp = (s * 2 + ks_s) * 32 + koff;
        lds[buf][ks_s * 256 + mf_s * 64 + lane] = cvt8(Ra0, Ra1, kp >> 9);
        if (tid < 256)
            lds[buf][512 + bks * 128 + bnf * 64 + lane] = R2;
    };

    f32x4 acc = {0.f, 0.f, 0.f, 0.f};

    stage(0);
    write_tile(0, 0);
    stage(1);
    __syncthreads();

    for (int s = 0; s < 24; ++s) {
        const int cur = s & 1;
        if (s + 1 < 24) write_tile(cur ^ 1, s + 1);
        if (s + 2 < 24) stage(s + 2);
        __builtin_amdgcn_sched_barrier(0);

        bf16x8 aF0 = *(const bf16x8*)&lds[cur][          mfw * 64 + lane];
        bf16x8 aF1 = *(const bf16x8*)&lds[cur][256     + mfw * 64 + lane];
        bf16x8 bF0 = *(const bf16x8*)&lds[cur][512     + nfw * 64 + lane];
        bf16x8 bF1 = *(const bf16x8*)&lds[cur][512+128 + nfw * 64 + lane];
        acc = __builtin_amdgcn_mfma_f32_16x16x32_bf16(aF0, bF0, acc, 0, 0, 0);
        acc = __builtin_amdgcn_mfma_f32_16x16x32_bf16(aF1, bF1, acc, 0, 0, 0);
        __syncthreads();
    }

    const int colg  = (nf0 + nfw) * 16 + (lane & 15);
    const float bv  = bias[colg];
    const int rbase = (mf0 + mfw) * 16 + ((lane >> 4) << 2);
    #pragma unroll
    for (int r = 0; r < 4; ++r) {
        float v = acc[r] + bv;
        if (ACT) { v = fmaxf(v, 0.f); v = v * v; }
        C[(size_t)(rbase + r) * 512 + colg] = v;
    }
}

// ---------------------------------------------------------------------------
// Sequential triangular scan, v13: v11 skeleton + R=2 rows/wave, P=4 parities.
// 512 blocks x 256 thr (4 waves); block owns rows R0=2b, R1=2b+1; wave p
// processes steps s == p (mod 4) of EVERY tile for BOTH rows. Each staged
// weight is applied to 2 rows (2 readlane + 6 VALU per ds_read) -> LDS
// traffic per row HALVED (the 15.5us floor -> 7.8). 2048 waves = 2/SIMD
// (v11's TLP). Staging, tile flow, barriers, pack: byte-identical to v11.
// Diag: wave 0 chains row R0, wave 1 chains row R1 CONCURRENTLY; partials
// (4 per row) combined at the chunk handoff via 2KB comm. Finals for row
// R0/R1 accumulate in wave 0/1 (diag wave never changes group k after
// chunk k -> it holds all finals at the end).
// FP note: group-C partial combine sums 4 parity partials (vs v11's 2) —
// same-magnitude reorder, empirically passing at r12's 0.03125.
// ---------------------------------------------------------------------------
template <int C>
__device__ __forceinline__ void scan_chunk(const float2* __restrict__ wdg,
                                           const float2* __restrict__ wbk,
                                           float2 (* __restrict__ smb)[3584],
                                           float (* __restrict__ comm)[4][64],
                                           float hA[8], float hB[8],
                                           int lane, int p, int tid) {
    constexpr int NK = 7 - C;
    constexpr int CB = (C==0?0:C==1?7:C==2?13:C==3?18:C==4?22:C==5?25:C==6?27:27) * 4096;

    const char* gch = (const char*)(wbk + CB);
    char* lbase = (char*)(&smb[0][0]) + ((tid >> 6) << 10);   // + wave*1024
    auto stage = [&](int t, int buf) {
        const char* g = gch + (size_t)t * (NK * 4096);
        char* l = lbase + buf * 28672;
        #pragma unroll
        for (int u = 0; u < NK; ++u)     // dest wave-uniform; HW adds lane*16
            gload_lds16(g + (size_t)((u << 8) + tid) * 16, l + (u << 12));
    };
    if constexpr (NK > 0) stage(0, 0);   // tile-0 flight hides under diag
    SB();

    // partial handoff: every wave ships its group-C partials for both rows
    if (p != 0) comm[0][p][lane] = hA[C];
    if (p != 1) comm[1][p][lane] = hB[C];
    __syncthreads();                     // also drains stage(0) vmcnt

    // serial diag: wave 0 -> row R0 (hA), wave 1 -> row R1 (hB), concurrent
    auto diag = [&](float& x) {
        const float2* dptr = wdg + (64 * C) * 64 + lane;
        float2 Wd[16];
        #pragma unroll
        for (int q = 0; q < 16; ++q) Wd[q] = dptr[q * 64];
        for (int t = 0; t < 4; ++t) {
            #pragma unroll
            for (int q = 0; q < 16; ++q) {
                const int s = t * 16 + q;
                if (!(C == 7 && s == 63)) {   // no global step 511
                    const float hi = __uint_as_float(
                        __builtin_amdgcn_readlane(__float_as_uint(x), s));
                    const float tv = fmaf(hi, Wd[q].x, Wd[q].y);
                    const float rv = fmaxf(tv, 0.f);
                    x = fmaf(rv, rv, x);
                }
                if (t < 3) Wd[q] = dptr[(s + 16) * 64];
            }
        }
    };
    if (p == 0) {
        hA[C] += comm[0][1][lane] + comm[0][2][lane] + comm[0][3][lane];
        diag(hA[C]);
        comm[0][0][lane] = hA[C];        // broadcast final, row R0
    } else if (p == 1) {
        hB[C] += comm[1][0][lane] + comm[1][2][lane] + comm[1][3][lane];
        diag(hB[C]);
        comm[1][1][lane] = hB[C];        // broadcast final, row R1
    }
    __syncthreads();

    // streaming bulk: finals ready -> all readlanes independent.
    // Wave p takes srow in {p, p+4} of every 8-step tile, for BOTH rows.
    if constexpr (NK > 0) {
        const float hsA = (p == 0) ? hA[C] : comm[0][0][lane];
        const float hsB = (p == 1) ? hB[C] : comm[1][1][lane];
        for (int t = 0; t < 8; ++t) {
            const int buf = t & 1;
            if (t + 1 < 8) stage(t + 1, buf ^ 1);
            SB();                        // pin staging above compute

            #pragma unroll
            for (int sl = 0; sl < 2; ++sl) {
                const int srow = p + 4 * sl;
                const int s = t * 8 + srow;
                const float hiA = __uint_as_float(
                    __builtin_amdgcn_readlane(__float_as_uint(hsA), s));
                const float hiB = __uint_as_float(
                    __builtin_amdgcn_readlane(__float_as_uint(hsB), s));
                #pragma unroll
                for (int k = 0; k < NK; ++k) {
                    const float2 wv = smb[buf][(srow * NK + k) * 64 + lane];
                    float tv = fmaf(hiA, wv.x, wv.y);
                    float rv = fmaxf(tv, 0.f);
                    hA[C + 1 + k] = fmaf(rv, rv, hA[C + 1 + k]);
                    tv = fmaf(hiB, wv.x, wv.y);
                    rv = fmaxf(tv, 0.f);
                    hB[C + 1 + k] = fmaf(rv, rv, hB[C + 1 + k]);
                }
            }
            __syncthreads();             // reads done; tile t+1 resident
        }
    }
}

__global__ __launch_bounds__(256, 2)
void scan_kernel(const float2* __restrict__ wdg, const float2* __restrict__ wbk,
                 float* __restrict__ h) {
    __shared__ __align__(16) float2 smb[2][3584];   // 2 x 28KB tile buffers
    __shared__ float comm[2][4][64];                // partial/final comm, 2KB
    const int tid  = threadIdx.x;
    const int lane = tid & 63;
    const int p    = tid >> 6;               // wave = s-parity (s mod 4)
    float* hrowA = h + (size_t)(blockIdx.x * 2    ) * HH;
    float* hrowB = h + (size_t)(blockIdx.x * 2 + 1) * HH;

    float hA[8], hB[8];
    #pragma unroll
    for (int k = 0; k < 8; ++k) {
        hA[k] = (p == 0) ? hrowA[lane + 64 * k] : 0.f;
        hB[k] = (p == 1) ? hrowB[lane + 64 * k] : 0.f;
    }

    scan_chunk<0>(wdg, wbk, smb, comm, hA, hB, lane, p, tid);
    scan_chunk<1>(wdg, wbk, smb, comm, hA, hB, lane, p, tid);
    scan_chunk<2>(wdg, wbk, smb, comm, hA, hB, lane, p, tid);
    scan_chunk<3>(wdg, wbk, smb, comm, hA, hB, lane, p, tid);
    scan_chunk<4>(wdg, wbk, smb, comm, hA, hB, lane, p, tid);
    scan_chunk<5>(wdg, wbk, smb, comm, hA, hB, lane, p, tid);
    scan_chunk<6>(wdg, wbk, smb, comm, hA, hB, lane, p, tid);
    scan_chunk<7>(wdg, wbk, smb, comm, hA, hB, lane, p, tid);

    // diag wave of chunk k holds the final for group k (never re-touched)
    if (p == 0) {
        #pragma unroll
        for (int k = 0; k < 8; ++k) hrowA[lane + 64 * k] = hA[k];
    } else if (p == 1) {
        #pragma unroll
        for (int k = 0; k < 8; ++k) hrowB[lane + 64 * k] = hB[k];
    }
}

// ---------------------------------------------------------------------------
// workspace layout (6.2 MB):
//   [0x000000, 0x040000) wdg  (512*64 f2 = 256 KB)
//   [0x040000, 0x120000) wbk  (114688 f2 = 896 KB, r11 pack)
//   [0x120000, 0x320000) h    (1024*512 fp32 = 2 MB)
//   [0x320000, 0x4A0000) Bin  (48*32*64 uint4 = 1.5 MB)
//   [0x4A0000, 0x620000) Bout (1.5 MB)
// ---------------------------------------------------------------------------
extern "C" void kernel_launch(void* const* d_in, const int* in_sizes, int n_in,
                              void* d_out, int out_size, void* d_ws, size_t ws_size,
                              hipStream_t stream) {
    const float* x     = (const float*)d_in[0];
    const float* W_in  = (const float*)d_in[1];
    const float* b_in  = (const float*)d_in[2];
    const float* W_hh  = (const float*)d_in[3];
    const float* b_hh  = (const float*)d_in[4];
    const float* W_out = (const float*)d_in[5];
    const float* b_out = (const float*)d_in[6];
    float* out = (float*)d_out;

    char* ws = (char*)d_ws;
    float2* wdg  = (float2*)ws;
    float2* wbk  = (float2*)(ws + 0x040000u);
    float*  h    = (float*)(ws + 0x120000u);
    uint4*  Bin  = (uint4*)(ws + 0x320000u);
    uint4*  Bout = (uint4*)(ws + 0x4A0000u);

    // 1) prep: scan-weight packs + W_in/W_out bf16 hi/lo frag-linear split
    prep_all<<<dim3(1344), dim3(256), 0, stream>>>(W_hh, b_hh, wdg, wbk,
                                                   W_in, Bin, W_out, Bout);

    // 2) h0 = relu^2(x @ W_in + b_in)  (A-side split fused into staging)
    mfma_gemm<true><<<dim3(16, 16), dim3(512), 0, stream>>>(x, Bin, b_in, h);

    // 3) sequential triangular scan, in-place on h (2 rows/wave, 4 parities)
    scan_kernel<<<dim3(512), dim3(256), 0, stream>>>(wdg, wbk, h);

    // 4) out = h @ W_out + b_out  (A-side split fused into staging)
    mfma_gemm<false><<<dim3(16, 16), dim3(512), 0, stream>>>(h, Bout, b_out, out);
}